// Round 2
// baseline (57.994 us; speedup 1.0000x reference)
//
#include <hip/hip_runtime.h>

#define BB 16
#define NN 768
#define NBOND 6144
#define BOTOLF 0.001f

typedef float f32x2 __attribute__((ext_vector_type(2)));

__device__ __forceinline__ float sigf(float z) {
    return 1.0f / (1.0f + __expf(-z));
}

// packed sigmoid: in z = {pre-activation, tangent}, out = {s, s'(z)*tangent}
__device__ __forceinline__ f32x2 sig2(f32x2 z) {
    float s = sigf(z.x);
    f32x2 r;
    r.x = s;
    r.y = s * (1.0f - s) * z.y;
    return r;
}

// bop value + d(bop)/dr as f32x2. ibo2 compile-time (6,5,4).
__device__ __forceinline__ f32x2 bop_calc(float r, float bo1, float r0, int ibo2)
{
    float t = r / r0;
    float t2 = t * t;
    float p;
    if (ibo2 == 6)      p = t2 * t2 * t2;
    else if (ibo2 == 5) p = t2 * t2 * t;
    else                p = t2 * t2;
    float e = (1.0f + BOTOLF) * __expf(bo1 * p);
    float de_dr = e * bo1 * (float)ibo2 * p / r;

    const float rmin = BOTOLF, rmax = 2.0f * BOTOLF;
    float T, dT;
    if (e > rmax) { T = 1.0f; dT = 0.0f; }
    else if (e > rmin) {
        const float rterm = -1.0e9f;           // 1/(rmin-rmax)^3
        float rd   = rmin - e;
        float trm1 = rmin + 2.0f * e - 3.0f * rmax;
        T  = rterm * rd * rd * trm1;
        dT = rterm * 2.0f * rd * (rd - trm1);
    } else { T = 0.0f; dT = 0.0f; }

    f32x2 out;
    out.x = T * (e - BOTOLF);
    out.y = (dT * (e - BOTOLF) + T) * de_dr;
    return out;
}

__global__ __launch_bounds__(64) void reaxff_bond_kernel(
    const float* __restrict__ x, const float* __restrict__ cell, const float* __restrict__ rcell,
    const float* __restrict__ fm_wi, const float* __restrict__ fm_bi,
    const float* __restrict__ fm_w,  const float* __restrict__ fm_b,
    const float* __restrict__ fm_wo, const float* __restrict__ fm_bo,
    const float* __restrict__ fe_wi, const float* __restrict__ fe_bi,
    const float* __restrict__ fe_w,  const float* __restrict__ fe_b,
    const float* __restrict__ fe_wo, const float* __restrict__ fe_bo,
    const float* __restrict__ desi_p, const int* __restrict__ bdid,
    float* __restrict__ out)   // out[0..15] = E, out[16..] = force (B,N,3)
{
    const int tid = threadIdx.x;
    const int blocks_per_batch = NBOND / 64;           // 96
    const int b = blockIdx.x / blocks_per_batch;
    const int k = (blockIdx.x % blocks_per_batch) * 64 + tid;

    // coalesced int2 load of bond indices
    const int2 bij = ((const int2*)bdid)[k];
    const int ai = bij.x;
    const int aj = bij.y;

    const float* cb = cell  + b * 9;
    const float* rb = rcell + b * 9;

    const float* xi = x + (size_t)(b * NN + ai) * 3;
    const float* xj = x + (size_t)(b * NN + aj) * 3;
    float u0 = xi[0] - xj[0];
    float u1 = xi[1] - xj[1];
    float u2 = xi[2] - xj[2];

    // f = u @ rcell  (rcell uniform -> SGPR)
    float f0 = u0 * rb[0] + u1 * rb[3] + u2 * rb[6];
    float f1 = u0 * rb[1] + u1 * rb[4] + u2 * rb[7];
    float f2 = u0 * rb[2] + u1 * rb[5] + u2 * rb[8];
    f0 = (f0 - 0.5f > 0.0f) ? f0 - 1.0f : f0;  f0 = (f0 + 0.5f < 0.0f) ? f0 + 1.0f : f0;
    f1 = (f1 - 0.5f > 0.0f) ? f1 - 1.0f : f1;  f1 = (f1 + 0.5f < 0.0f) ? f1 + 1.0f : f1;
    f2 = (f2 - 0.5f > 0.0f) ? f2 - 1.0f : f2;  f2 = (f2 + 0.5f < 0.0f) ? f2 + 1.0f : f2;
    float v0 = f0 * cb[0] + f1 * cb[3] + f2 * cb[6];
    float v1 = f0 * cb[1] + f1 * cb[4] + f2 * cb[7];
    float v2 = f0 * cb[2] + f1 * cb[5] + f2 * cb[8];

    float r = sqrtf(v0 * v0 + v1 * v1 + v2 * v2 + 1e-8f);

    // mv = (rcell @ cell) @ vr
    float cv0 = cb[0] * v0 + cb[1] * v1 + cb[2] * v2;
    float cv1 = cb[3] * v0 + cb[4] * v1 + cb[5] * v2;
    float cv2 = cb[6] * v0 + cb[7] * v1 + cb[8] * v2;
    float mv0 = rb[0] * cv0 + rb[1] * cv1 + rb[2] * cv2;
    float mv1 = rb[3] * cv0 + rb[4] * cv1 + rb[5] * cv2;
    float mv2 = rb[6] * cv0 + rb[7] * cv1 + rb[8] * cv2;

    // ---- bond-order features (value, d/dr) ----
    f32x2 h3[3];
    h3[0] = bop_calc(r, -0.077f, 1.39f, 6);
    h3[1] = bop_calc(r, -0.15f,  1.30f, 5);
    h3[2] = bop_calc(r, -0.30f,  1.25f, 4);

    // ---- MLP 1 (fm): 3 -> 9 -> (5x) 9 -> 3 ---- weights via s_load (uniform)
    f32x2 h[9];
    #pragma unroll
    for (int jj = 0; jj < 9; jj++) {
        f32x2 z; z.x = fm_bi[jj]; z.y = 0.0f;
        #pragma unroll
        for (int kk = 0; kk < 3; kk++) {
            float wv = fm_wi[kk * 9 + jj];
            z += h3[kk] * wv;
        }
        h[jj] = sig2(z);
    }
    #pragma unroll
    for (int l = 0; l < 5; l++) {
        const float* wl = fm_w + l * 81;
        const float* bl = fm_b + l * 9;
        f32x2 hn[9];
        #pragma unroll
        for (int jj = 0; jj < 9; jj++) {
            f32x2 z; z.x = bl[jj]; z.y = 0.0f;
            #pragma unroll
            for (int kk = 0; kk < 9; kk++) {
                float wv = wl[kk * 9 + jj];
                z += h[kk] * wv;
            }
            hn[jj] = sig2(z);
        }
        #pragma unroll
        for (int jj = 0; jj < 9; jj++) h[jj] = hn[jj];
    }
    f32x2 bo3[3];
    #pragma unroll
    for (int jj = 0; jj < 3; jj++) {
        f32x2 z; z.x = fm_bo[jj]; z.y = 0.0f;
        #pragma unroll
        for (int kk = 0; kk < 9; kk++) {
            float wv = fm_wo[kk * 3 + jj];
            z += h[kk] * wv;
        }
        bo3[jj] = sig2(z);
    }

    // ---- MLP 2 (fe): 3 -> 8 -> (5x) 8 -> 1 ----
    f32x2 g8[8];
    #pragma unroll
    for (int jj = 0; jj < 8; jj++) {
        f32x2 z; z.x = fe_bi[jj]; z.y = 0.0f;
        #pragma unroll
        for (int kk = 0; kk < 3; kk++) {
            float wv = fe_wi[kk * 8 + jj];
            z += bo3[kk] * wv;
        }
        g8[jj] = sig2(z);
    }
    #pragma unroll
    for (int l = 0; l < 5; l++) {
        const float* wl = fe_w + l * 64;
        const float* bl = fe_b + l * 8;
        f32x2 gn[8];
        #pragma unroll
        for (int jj = 0; jj < 8; jj++) {
            f32x2 z; z.x = bl[jj]; z.y = 0.0f;
            #pragma unroll
            for (int kk = 0; kk < 8; kk++) {
                float wv = wl[kk * 8 + jj];
                z += g8[kk] * wv;
            }
            gn[jj] = sig2(z);
        }
        #pragma unroll
        for (int jj = 0; jj < 8; jj++) g8[jj] = gn[jj];
    }
    f32x2 z; z.x = fe_bo[0]; z.y = 0.0f;
    #pragma unroll
    for (int kk = 0; kk < 8; kk++) {
        float wv = fe_wo[kk];
        z += g8[kk] * wv;
    }
    f32x2 esi = sig2(z);   // {esi, d(esi)/dr}

    // ---- energy + force ----
    float D   = desi_p[0];
    float ebd = -D * esi.x;          // per-bond energy
    float g   = -D * esi.y;          // dE_bond/dr
    float inv_r = 1.0f / r;
    float G0 = g * mv0 * inv_r;
    float G1 = g * mv1 * inv_r;
    float G2 = g * mv2 * inv_r;

    float* force = out + BB;
    float* fi = force + (size_t)(b * NN + ai) * 3;
    float* fj = force + (size_t)(b * NN + aj) * 3;
    atomicAdd(&fi[0], -G0);
    atomicAdd(&fi[1], -G1);
    atomicAdd(&fi[2], -G2);
    atomicAdd(&fj[0],  G0);
    atomicAdd(&fj[1],  G1);
    atomicAdd(&fj[2],  G2);

    // ---- per-wave energy reduction (block == 1 wave) ----
    float e = ebd;
    #pragma unroll
    for (int off = 32; off > 0; off >>= 1) e += __shfl_down(e, off, 64);
    if (tid == 0) atomicAdd(&out[b], e);
}

extern "C" void kernel_launch(void* const* d_in, const int* in_sizes, int n_in,
                              void* d_out, int out_size, void* d_ws, size_t ws_size,
                              hipStream_t stream)
{
    // zero E + force accumulators (atomics accumulate; harness never re-poisons)
    hipMemsetAsync(d_out, 0, (size_t)out_size * sizeof(float), stream);

    dim3 grid(BB * (NBOND / 64));   // 1536 blocks, 1 wave each -> 6 waves/CU even
    dim3 block(64);
    reaxff_bond_kernel<<<grid, block, 0, stream>>>(
        (const float*)d_in[0],  (const float*)d_in[1],  (const float*)d_in[2],
        (const float*)d_in[3],  (const float*)d_in[4],  (const float*)d_in[5],
        (const float*)d_in[6],  (const float*)d_in[7],  (const float*)d_in[8],
        (const float*)d_in[9],  (const float*)d_in[10], (const float*)d_in[11],
        (const float*)d_in[12], (const float*)d_in[13], (const float*)d_in[14],
        (const float*)d_in[15], (const int*)d_in[16],
        (float*)d_out);
}